// Round 9
// baseline (46415.042 us; speedup 1.0000x reference)
//
#include <hip/hip_runtime.h>

// Problem constants
#define BB 16
#define SS 2048
#define DD 256
#define ND4 1024   // 4*D
#define PRD 16     // R-buffer slot depth (residual stream)
#define PGD 8      // GX-buffer slot depth (gate pre-activations)
#define HLP 8      // helper WGs per layer (one per GX slot)

typedef __attribute__((ext_vector_type(8))) _Float16 half8;
typedef __attribute__((ext_vector_type(4))) float f32x4;
typedef unsigned long long u64;
union H8 { half8 v; unsigned int u[4]; uint4 q; };

__device__ __forceinline__ u64 aload(const u64* p) {
    return __hip_atomic_load(p, __ATOMIC_RELAXED, __HIP_MEMORY_SCOPE_AGENT);
}
__device__ __forceinline__ void astore(u64* p, u64 v) {
    __hip_atomic_store(p, v, __ATOMIC_RELAXED, __HIP_MEMORY_SCOPE_AGENT);
}
__device__ __forceinline__ unsigned pload(const unsigned* p) {
    return __hip_atomic_load(p, __ATOMIC_RELAXED, __HIP_MEMORY_SCOPE_AGENT);
}
__device__ __forceinline__ void pstore(unsigned* p, unsigned v) {
    __hip_atomic_store(p, v, __ATOMIC_RELAXED, __HIP_MEMORY_SCOPE_AGENT);
}
__device__ __forceinline__ int aflag(int* p) {
    return __hip_atomic_load(p, __ATOMIC_RELAXED, __HIP_MEMORY_SCOPE_AGENT);
}
__device__ __forceinline__ void sflag(int* p) {
    __hip_atomic_store(p, 1, __ATOMIC_RELAXED, __HIP_MEMORY_SCOPE_AGENT);
}
__device__ __forceinline__ unsigned short f16b(float x) {
    union { _Float16 h; unsigned short u; } c; c.h = (_Float16)x; return c.u;
}
__device__ __forceinline__ unsigned umin2(unsigned a, unsigned b) { return a < b ? a : b; }
// LDS-only barrier: __syncthreads() emits a full vmcnt(0) drain [HIP-compiler];
// scan's barrier only protects LDS, so lgkmcnt(0) + raw s_barrier suffices and
// leaves the agent prefetch/stores in flight.
__device__ __forceinline__ void ldsBar() {
    asm volatile("s_waitcnt lgkmcnt(0)" ::: "memory");
    __builtin_amdgcn_s_barrier();
}
// spin guard with backoff (steady-state: first-try hit)
__device__ __forceinline__ bool spinBail(int& guard, int* af) {
    if ((++guard & 63) == 0) {
        __builtin_amdgcn_s_sleep(1);
        if (guard > (1 << 18) || aflag(af)) { sflag(af); return true; }
    }
    return false;
}

// ---------------------------------------------------------------------------
// embed: h0 = [x | tf] @ in_W + in_b
// ---------------------------------------------------------------------------
__global__ void embed_kernel(const float* __restrict__ x, const float* __restrict__ tf,
                             const float* __restrict__ inW, const float* __restrict__ inb,
                             float* __restrict__ h) {
    int tok = blockIdx.x, d = threadIdx.x;
    float xv = x[tok];
    float acc = inb[d] + xv * inW[d];
#pragma unroll
    for (int c = 0; c < 6; ++c)
        acc = fmaf(tf[tok * 6 + c], inW[(c + 1) * DD + d], acc);
    h[(size_t)tok * DD + d] = acc;
}

// ---------------------------------------------------------------------------
// Wx -> fp16 B-fragment order: Wxh[((l*64+G)*8+kc)*64 + lane][8]
// ---------------------------------------------------------------------------
__global__ void wxprep_kernel(const float* __restrict__ Wx, unsigned short* __restrict__ Wxh) {
    int l = blockIdx.x >> 6, G = blockIdx.x & 63;
    int lane = threadIdx.x, quad = lane >> 4, mm = lane & 15;
    const float* W = Wx + (size_t)l * DD * ND4;
    unsigned short* o = Wxh + (size_t)blockIdx.x * 4096;
#pragma unroll
    for (int kc = 0; kc < 8; ++kc) {
        __align__(16) unsigned short tmp[8];
#pragma unroll
        for (int i = 0; i < 8; ++i)
            tmp[i] = f16b(W[(size_t)(kc * 32 + quad * 8 + i) * ND4 + G * 16 + mm]);
        *(uint4*)(o + ((size_t)kc * 64 + lane) * 8) = *(uint4*)tmp;
    }
}

// ---------------------------------------------------------------------------
// Mega kernel R9: 36 WGs x 1024 thr.
//   bid 0..3  : SCAN, one 1024-thread WG per layer. The entire sLSTM scan for
//               a layer runs on ONE CU: 16 waves, wave w owns col-tiles
//               {w*16, 256+w*16, 512+w*16, 768+w*16} so all 4 gates of a state
//               dim live in one wave's accumulators; lane (quad,mm) owns
//               4 batches (quad*4+r) x dim (w*16+mm). h(t) is exchanged via an
//               8KB double-buffered LDS tile + ONE lgkmcnt-only barrier/token.
//               -> the cross-WG X exchange (measured ~3us/step, R0-R8) is GONE.
//   bid 4..35 : helper (l=(bid-4)>>3, j=(bid-4)&7): proven streaming gx GEMM,
//               256 active threads; idle waves run a barrier-matching loop.
// Inter-layer R/GX handoff: unchanged tagged agent-scope protocol (prefetched
// one token ahead, tag-checked, cached monotone gates) -> constant pipeline
// skew, not per-token cost.
// LDS swizzle: hbuf element (b,d) at byte b*512 + ((2d) ^ ((b&7)<<4)); A-frag
// read (lane quad,mm; chunk kc) = 16B at mm*512 + ((kc*64+quad*16)^((mm&7)<<4))
// -> dims kc*32+quad*8..+7, batch mm: exactly the 16x16x32 A layout; 8 lanes
// per 16B slot uniform -> conflict-free.
// ---------------------------------------------------------------------------
__global__ __launch_bounds__(1024, 1) void mega_kernel(
    const float* __restrict__ hemb, const float* __restrict__ Wh,
    const float* __restrict__ lng, const float* __restrict__ lnb,
    const float* __restrict__ bgp, const unsigned short* __restrict__ Wxh,
    float* __restrict__ hout,
    u64* __restrict__ Rbuf, u64* __restrict__ GXbuf,
    unsigned* __restrict__ prog, int* __restrict__ abortFlag) {
    __shared__ __align__(16) char smemBlob[16640];
    const int bid = blockIdx.x;
    const int tid = threadIdx.x;

    if (bid < 4) {
        // ================= SCAN: whole layer in one WG =================
        const int l = bid;
        const int w = tid >> 6;        // wave id 0..15 = col-group
        const int lane = tid & 63;
        const int quad = lane >> 4, mm = lane & 15;
        const int d = w * 16 + mm;     // owned state dim
        const int b0 = quad * 4;       // first of 4 owned batches
        unsigned short* hb0 = (unsigned short*)smemBlob;           // [16][256] f16
        unsigned short* hb1 = (unsigned short*)(smemBlob + 8192);

        // Wh fragments: 4 gate-tiles x 8 K-chunks (128 VGPR)
        H8 bfr[4][8];
        {
            const float* WhL = Wh + (size_t)l * DD * ND4;
#pragma unroll
            for (int tau = 0; tau < 4; ++tau) {
                const int col = tau * 256 + d;
#pragma unroll
                for (int kc = 0; kc < 8; ++kc)
#pragma unroll
                    for (int p = 0; p < 4; ++p) {
                        float f0 = WhL[(size_t)(32 * kc + 8 * quad + 2 * p) * ND4 + col];
                        float f1 = WhL[(size_t)(32 * kc + 8 * quad + 2 * p + 1) * ND4 + col];
                        bfr[tau][kc].u[p] = (unsigned)f16b(f0) | ((unsigned)f16b(f1) << 16);
                    }
            }
        }

        const u64* Rprev = Rbuf + (size_t)(l > 0 ? l - 1 : 0) * PRD * 4096;
        u64* Rcur = Rbuf + (size_t)(l < 3 ? l : 0) * PRD * 4096;
        const u64* GXl = GXbuf + (size_t)l * PGD * 16384;

        // progress-gate caches (monotone lower bounds)
        unsigned psC = 0, minPgC = 0;
        const unsigned* psP = prog + (l + 1);
        const unsigned* pgP = prog + 4 + (l + 1) * 8;

        // tagged prefetch state: 16 gx (4 batches x 4 gates) + 4 residual
        u64 pf[16]; u64 pr[4]; float ph[4];
        auto loadSlot = [&](int t1) {
            const u64* Gp = GXl + (size_t)(t1 & (PGD - 1)) * 16384;
#pragma unroll
            for (int r = 0; r < 4; ++r)
#pragma unroll
                for (int gg = 0; gg < 4; ++gg)
                    pf[r * 4 + gg] = aload(Gp + (size_t)(b0 + r) * 1024 + gg * 256 + d);
            if (l > 0) {
                const u64* Rp = Rprev + (size_t)(t1 & (PRD - 1)) * 4096;
#pragma unroll
                for (int r = 0; r < 4; ++r)
                    pr[r] = aload(Rp + (size_t)(b0 + r) * 256 + d);
            } else {
#pragma unroll
                for (int r = 0; r < 4; ++r)
                    ph[r] = hemb[((size_t)(b0 + r) * SS + t1) * DD + d];
            }
        };
        auto tagsOK = [&](unsigned tagT) {
            bool ok = true;
#pragma unroll
            for (int i = 0; i < 16; ++i) ok &= ((unsigned)(pf[i] >> 32) == tagT);
            if (l > 0) {
#pragma unroll
                for (int r = 0; r < 4; ++r) ok &= ((unsigned)(pr[r] >> 32) == tagT);
            }
            return ok;
        };

        loadSlot(0);
        float c_[4] = {0.f, 0.f, 0.f, 0.f};
        float n_[4] = {0.f, 0.f, 0.f, 0.f};
        float m_[4] = {0.f, 0.f, 0.f, 0.f};

        for (int t = 0; t < SS; ++t) {
            const unsigned tagT = (unsigned)(t + 1);
            // ---- acquire gx + hin (prefetched last step; poll on miss) ----
            if (!tagsOK(tagT)) {
                int guard = 0;
                for (;;) {
                    loadSlot(t);
                    if (tagsOK(tagT)) break;
                    if (spinBail(guard, abortFlag)) break;
                }
            }
            float gxv[16], hin[4];
#pragma unroll
            for (int i = 0; i < 16; ++i) gxv[i] = __uint_as_float((unsigned)pf[i]);
#pragma unroll
            for (int r = 0; r < 4; ++r)
                hin[r] = (l > 0) ? __uint_as_float((unsigned)pr[r]) : ph[r];
            // early progress post (slot t&7 protected until prog=t+2)
            if (tid == 0) pstore(prog + l, (unsigned)(t + 1));
            // prefetch t+1: flies under MFMA + gates (never drained: ldsBar
            // is lgkmcnt-only; consumed via tag check next step)
            loadSlot(t + 1 < SS ? t + 1 : t);

            // ---- Wh matmul on h(t-1) from LDS (intra-WG exchange) ----
            f32x4 a0 = {0.f,0.f,0.f,0.f}, a1 = {0.f,0.f,0.f,0.f};
            f32x4 a2 = {0.f,0.f,0.f,0.f}, a3 = {0.f,0.f,0.f,0.f};
            if (t > 0) {
                const char* hb = (t & 1) ? (const char*)hb1 : (const char*)hb0;
                const int rb = mm * 512;
                const int sw = (mm & 7) << 4;
#pragma unroll
                for (int kc = 0; kc < 8; ++kc) {
                    H8 a;
                    a.q = *(const uint4*)(hb + rb + ((kc * 64 + quad * 16) ^ sw));
                    a0 = __builtin_amdgcn_mfma_f32_16x16x32_f16(a.v, bfr[0][kc].v, a0, 0, 0, 0);
                    a1 = __builtin_amdgcn_mfma_f32_16x16x32_f16(a.v, bfr[1][kc].v, a1, 0, 0, 0);
                    a2 = __builtin_amdgcn_mfma_f32_16x16x32_f16(a.v, bfr[2][kc].v, a2, 0, 0, 0);
                    a3 = __builtin_amdgcn_mfma_f32_16x16x32_f16(a.v, bfr[3][kc].v, a3, 0, 0, 0);
                }
            }

            // ---- gates + state + h publish (all 4 gates lane-local) ----
            char* hbN = ((t + 1) & 1) ? (char*)hb1 : (char*)hb0;
            float rnew[4];
#pragma unroll
            for (int r = 0; r < 4; ++r) {
                float gi = a0[r] + gxv[r * 4 + 0];
                float gf = a1[r] + gxv[r * 4 + 1];
                float gz = a2[r] + gxv[r * 4 + 2];
                float go = a3[r] + gxv[r * 4 + 3];
                float mn = fmaxf(gf + m_[r], gi);
                float ip = __expf(gi - mn);
                float fp = __expf(gf + m_[r] - mn);
                float e2z = __expf(2.f * gz);
                float th = 1.f - 2.f * __builtin_amdgcn_rcpf(e2z + 1.f);
                c_[r] = fp * c_[r] + ip * th;
                n_[r] = fp * n_[r] + ip;
                m_[r] = mn;
                float sg = __builtin_amdgcn_rcpf(1.f + __expf(-go));
                float hval = sg * c_[r] * __builtin_amdgcn_rcpf(fmaxf(fabsf(n_[r]), 1.f));
                rnew[r] = hin[r] + hval;
                const int b = b0 + r;
                *(unsigned short*)(hbN + b * 512 + ((d * 2) ^ ((b & 7) << 4))) = f16b(hval);
            }

            // ---- residual out (tagged agent handoff to next layer) ----
            if (l == 3) {
#pragma unroll
                for (int r = 0; r < 4; ++r)
                    hout[((size_t)(b0 + r) * SS + t) * DD + d] = rnew[r];
            } else {
                if (t >= PRD) {  // slot-reuse gate, cached (counters monotone)
                    unsigned needT = (unsigned)(t - PRD);
                    if (!((psC >= needT + 2) & (minPgC >= needT + 1))) {
                        int guard = 0;
                        for (;;) {
                            unsigned a = pload(psP);
                            unsigned mn8 = pload(pgP + 0);
#pragma unroll
                            for (int i = 1; i < 8; ++i) mn8 = umin2(mn8, pload(pgP + i));
                            psC = a; minPgC = mn8;
                            if ((a >= needT + 2) & (mn8 >= needT + 1)) break;
                            if (spinBail(guard, abortFlag)) break;
                        }
                    }
                }
                u64* Rq = Rcur + (size_t)(t & (PRD - 1)) * 4096;
#pragma unroll
                for (int r = 0; r < 4; ++r)
                    astore(Rq + (size_t)(b0 + r) * 256 + d,
                           ((u64)tagT << 32) | (u64)__float_as_uint(rnew[r]));
            }
            // single per-token barrier: hbN writes visible for t+1 reads; WAR
            // on the other parity buffer separated by the previous barrier
            ldsBar();
        }
    } else {
        // ================= HELPER ROLE: streaming gx GEMM =================
        const int hix = bid - 4;
        const int l = hix >> 3;
        const int j = hix & 7;
        if (tid >= 256) {
            // idle waves: match the active waves' barrier count exactly
            for (int t = j; t < SS; t += HLP) { __syncthreads(); __syncthreads(); }
            return;
        }
        const int w = tid >> 6, lane = tid & 63;
        const int mm = lane & 15, quad = lane >> 4;
        const int hb_ = tid >> 4, hd0 = (tid & 15) * 16;
        unsigned short (*hA)[264] = (unsigned short (*)[264])smemBlob;

        const u64* Rin = Rbuf + (size_t)(l > 0 ? l - 1 : 0) * PRD * 4096;
        u64* GXl = GXbuf + (size_t)l * PGD * 16384;
        const unsigned short* WxL = Wxh + (size_t)l * 262144;
        const float* lngL = lng + l * DD;
        const float* lnbL = lnb + l * DD;
        const float* bgL = bgp + (size_t)l * ND4;
        unsigned* myProg = prog + 4 + l * 8 + j;
        const unsigned* scanProg = prog + l;
        unsigned spC = 0;  // cached lower bound of scan progress

        for (int t = j; t < SS; t += HLP) {
            const unsigned tagT = (unsigned)(t + 1);
            // ---- 1. acquire r[l-1][t] (or embed for l==0) ----
            float rv[16];
            if (l == 0) {
                const float4* p = (const float4*)(hemb + ((size_t)hb_ * SS + t) * DD + hd0);
#pragma unroll
                for (int q4 = 0; q4 < 4; ++q4) {
                    float4 f = p[q4];
                    rv[q4 * 4 + 0] = f.x; rv[q4 * 4 + 1] = f.y;
                    rv[q4 * 4 + 2] = f.z; rv[q4 * 4 + 3] = f.w;
                }
            } else {
                const u64* Rp = Rin + (size_t)(t & (PRD - 1)) * 4096 + (size_t)tid * 16;
                int guard = 0;
                for (;;) {
                    u64 vv[16];
#pragma unroll
                    for (int i = 0; i < 16; ++i) vv[i] = aload(Rp + i);
                    bool ok = true;
#pragma unroll
                    for (int i = 0; i < 16; ++i) ok &= ((unsigned)(vv[i] >> 32) == tagT);
                    if (ok) {
#pragma unroll
                        for (int i = 0; i < 16; ++i) rv[i] = __uint_as_float((unsigned)vv[i]);
                        break;
                    }
                    if (spinBail(guard, abortFlag)) {
#pragma unroll
                        for (int i = 0; i < 16; ++i) rv[i] = 0.f;
                        break;
                    }
                }
            }
            // ---- 2. LN stats (16 threads per batch, shfl-xor reduce) ----
            float s = 0.f, ssq = 0.f;
#pragma unroll
            for (int i = 0; i < 16; ++i) { s += rv[i]; ssq += rv[i] * rv[i]; }
#pragma unroll
            for (int msk = 1; msk < 16; msk <<= 1) {
                s += __shfl_xor(s, msk);
                ssq += __shfl_xor(ssq, msk);
            }
            float muv = s * (1.f / 256.f);
            float rsv = rsqrtf(fmaxf(ssq * (1.f / 256.f) - muv * muv, 0.f) + 1e-5f);
            // ---- 3. LN -> fp16 -> LDS (A-matrix rows = batches) ----
            {
                __align__(16) unsigned short ov[16];
#pragma unroll
                for (int i = 0; i < 16; ++i)
                    ov[i] = f16b((rv[i] - muv) * rsv * lngL[hd0 + i] + lnbL[hd0 + i]);
                *(uint4*)&hA[hb_][hd0] = *(uint4*)&ov[0];
                *(uint4*)&hA[hb_][hd0 + 8] = *(uint4*)&ov[8];
            }
            __syncthreads();
            // early post: this sync covers every thread's R-read for token t
            if (tid == 0) pstore(myProg, (unsigned)(t + 1));
            // ---- 4. A-frags from LDS ----
            H8 A[8];
#pragma unroll
            for (int kc = 0; kc < 8; ++kc)
                A[kc].q = *(const uint4*)&hA[mm][kc * 32 + quad * 8];
            // ---- 5. 16 tiles x 8 chunks MFMA, B streamed from L2 ----
            f32x4 acc[16];
            const unsigned short* WxW = WxL + (size_t)w * 16 * 4096;
#pragma unroll
            for (int n = 0; n < 16; ++n) {
                const unsigned short* bp = WxW + (size_t)n * 4096 + (size_t)lane * 8;
                f32x4 a = {0.f, 0.f, 0.f, 0.f};
#pragma unroll
                for (int kc = 0; kc < 8; ++kc) {
                    H8 B;
                    B.q = *(const uint4*)(bp + (size_t)kc * 512);
                    a = __builtin_amdgcn_mfma_f32_16x16x32_f16(A[kc].v, B.v, a, 0, 0, 0);
                }
                acc[n] = a;
            }
            // ---- 6. slot-reuse gate (cached), then write GX ----
            if (t >= PGD) {
                unsigned need = (unsigned)(t - PGD) + 2;
                if (spC < need) {
                    int guard = 0;
                    for (;;) {
                        unsigned v = pload(scanProg);
                        spC = v;
                        if (v >= need) break;
                        if (spinBail(guard, abortFlag)) break;
                    }
                }
            }
            u64* Gq = GXl + (size_t)(t & (PGD - 1)) * 16384;
#pragma unroll
            for (int n = 0; n < 16; ++n) {
                int c = (w * 16 + n) * 16 + mm;
                float bgv = bgL[c];
                f32x4 a = acc[n];
#pragma unroll
                for (int r = 0; r < 4; ++r)
                    astore(Gq + (size_t)(quad * 4 + r) * 1024 + c,
                           ((u64)tagT << 32) | (u64)__float_as_uint(a[r] + bgv));
            }
            __syncthreads();  // covers hA WAR for next token
        }
    }
}

// ---------------------------------------------------------------------------
// final: out[b] = r3[b][S-1][:] . fc_W + fc_b
// ---------------------------------------------------------------------------
__global__ void final_kernel(const float* __restrict__ h, const float* __restrict__ fcW,
                             const float* __restrict__ fcb, float* __restrict__ out) {
    int b = blockIdx.x, lane = threadIdx.x;
    const float4 hv = *(const float4*)(h + ((size_t)b * SS + (SS - 1)) * DD + lane * 4);
    const float4 wv = *(const float4*)(fcW + lane * 4);
    float s = hv.x * wv.x + hv.y * wv.y + hv.z * wv.z + hv.w * wv.w;
#pragma unroll
    for (int off = 32; off; off >>= 1) s += __shfl_down(s, off);
    if (lane == 0) out[b] = s + fcb[0];
}

// ---------------------------------------------------------------------------
extern "C" void kernel_launch(void* const* d_in, const int* in_sizes, int n_in,
                              void* d_out, int out_size, void* d_ws, size_t ws_size,
                              hipStream_t stream) {
    const float* x   = (const float*)d_in[0];
    const float* tf  = (const float*)d_in[1];
    const float* inW = (const float*)d_in[2];
    const float* inb = (const float*)d_in[3];
    const float* lng = (const float*)d_in[4];
    const float* lnb = (const float*)d_in[5];
    const float* Wx  = (const float*)d_in[6];
    const float* Wh  = (const float*)d_in[7];
    const float* bg  = (const float*)d_in[8];
    const float* fcW = (const float*)d_in[9];
    const float* fcb = (const float*)d_in[10];
    float* out = (float*)d_out;

    const size_t nTok = (size_t)BB * SS;
    float* hemb = (float*)d_ws;                                   // 8,388,608 f
    float* hout = hemb + nTok * DD;                               // 8,388,608 f
    unsigned short* Wxh = (unsigned short*)(hout + nTok * DD);    // 1,048,576 us
    u64* Rbuf = (u64*)(Wxh + 1048576);                            // 3*16*4096
    u64* GXbuf = Rbuf + 3 * PRD * 4096;                           // 4*8*16384
    // prog area: [0..3]=scan progress, [4..35]=helper progress, [40]=abort
    unsigned* prog = (unsigned*)(GXbuf + 4 * PGD * 16384);
    int* abortFlag = (int*)(prog + 40);

    const size_t needed = (size_t)((char*)(prog + 64) - (char*)d_ws);
    if (ws_size < needed) return;  // fail visibly instead of corrupting

    hipMemsetAsync(prog, 0, 64 * sizeof(unsigned), stream);
    // R/GX need no init: 0xAA poison never matches a tag in [1,2048]

    embed_kernel<<<nTok, DD, 0, stream>>>(x, tf, inW, inb, hemb);
    wxprep_kernel<<<4 * 64, 64, 0, stream>>>(Wx, Wxh);
    mega_kernel<<<36, 1024, 0, stream>>>(hemb, Wh, lng, lnb, bg, Wxh, hout,
                                         Rbuf, GXbuf, prog, abortFlag);
    final_kernel<<<BB, 64, 0, stream>>>(hout, fcW, fcb, out);
    (void)in_sizes; (void)n_in; (void)out_size;
}

// Round 10
// 19371.104 us; speedup vs baseline: 2.3961x; 2.3961x over previous
//
#include <hip/hip_runtime.h>

// Problem constants
#define BB 16
#define SS 2048
#define DD 256
#define ND4 1024   // 4*D
#define PRD 16     // R-buffer slot depth (residual stream)
#define PGD 8      // GX-buffer slot depth (gate pre-activations)
#define HLP 8      // helper WGs per layer (one per GX slot)

typedef __attribute__((ext_vector_type(8))) _Float16 half8;
typedef __attribute__((ext_vector_type(4))) float f32x4;
typedef unsigned long long u64;
union H8 { half8 v; unsigned int u[4]; uint4 q; };

__device__ __forceinline__ u64 aload(const u64* p) {
    return __hip_atomic_load(p, __ATOMIC_RELAXED, __HIP_MEMORY_SCOPE_AGENT);
}
__device__ __forceinline__ void astore(u64* p, u64 v) {
    __hip_atomic_store(p, v, __ATOMIC_RELAXED, __HIP_MEMORY_SCOPE_AGENT);
}
__device__ __forceinline__ unsigned pload(const unsigned* p) {
    return __hip_atomic_load(p, __ATOMIC_RELAXED, __HIP_MEMORY_SCOPE_AGENT);
}
__device__ __forceinline__ void pstore(unsigned* p, unsigned v) {
    __hip_atomic_store(p, v, __ATOMIC_RELAXED, __HIP_MEMORY_SCOPE_AGENT);
}
__device__ __forceinline__ int aflag(int* p) {
    return __hip_atomic_load(p, __ATOMIC_RELAXED, __HIP_MEMORY_SCOPE_AGENT);
}
__device__ __forceinline__ void sflag(int* p) {
    __hip_atomic_store(p, 1, __ATOMIC_RELAXED, __HIP_MEMORY_SCOPE_AGENT);
}
__device__ __forceinline__ unsigned short f16b(float x) {
    union { _Float16 h; unsigned short u; } c; c.h = (_Float16)x; return c.u;
}
__device__ __forceinline__ unsigned umin2(unsigned a, unsigned b) { return a < b ? a : b; }
// LDS-only barrier: __syncthreads() emits a full vmcnt(0) drain [HIP-compiler];
// scan's barriers only protect LDS, so lgkmcnt(0) + raw s_barrier suffices and
// leaves the agent prefetch/stores in flight.
__device__ __forceinline__ void ldsBar() {
    asm volatile("s_waitcnt lgkmcnt(0)" ::: "memory");
    __builtin_amdgcn_s_barrier();
}
// spin guard with backoff (steady-state: first-try hit)
__device__ __forceinline__ bool spinBail(int& guard, int* af) {
    if ((++guard & 63) == 0) {
        __builtin_amdgcn_s_sleep(1);
        if (guard > (1 << 18) || aflag(af)) { sflag(af); return true; }
    }
    return false;
}

// ---------------------------------------------------------------------------
// embed: h0 = [x | tf] @ in_W + in_b
// ---------------------------------------------------------------------------
__global__ void embed_kernel(const float* __restrict__ x, const float* __restrict__ tf,
                             const float* __restrict__ inW, const float* __restrict__ inb,
                             float* __restrict__ h) {
    int tok = blockIdx.x, d = threadIdx.x;
    float xv = x[tok];
    float acc = inb[d] + xv * inW[d];
#pragma unroll
    for (int c = 0; c < 6; ++c)
        acc = fmaf(tf[tok * 6 + c], inW[(c + 1) * DD + d], acc);
    h[(size_t)tok * DD + d] = acc;
}

// ---------------------------------------------------------------------------
// Wx -> fp16 B-fragment order: Wxh[((l*64+G)*8+kc)*64 + lane][8]
// ---------------------------------------------------------------------------
__global__ void wxprep_kernel(const float* __restrict__ Wx, unsigned short* __restrict__ Wxh) {
    int l = blockIdx.x >> 6, G = blockIdx.x & 63;
    int lane = threadIdx.x, quad = lane >> 4, mm = lane & 15;
    const float* W = Wx + (size_t)l * DD * ND4;
    unsigned short* o = Wxh + (size_t)blockIdx.x * 4096;
#pragma unroll
    for (int kc = 0; kc < 8; ++kc) {
        __align__(16) unsigned short tmp[8];
#pragma unroll
        for (int i = 0; i < 8; ++i)
            tmp[i] = f16b(W[(size_t)(kc * 32 + quad * 8 + i) * ND4 + G * 16 + mm]);
        *(uint4*)(o + ((size_t)kc * 64 + lane) * 8) = *(uint4*)tmp;
    }
}

// ---------------------------------------------------------------------------
// Mega kernel R10: 48 WGs x 512 thr, waves_per_eu(2,2) (256-VGPR budget) +
// 82KB LDS (1 WG/CU). R9 lesson: Wh (512KB/layer) cannot fit one CU's 512KB
// register file -> shard over 4 CUs, 64 VGPR/lane for Wh (verified fits).
//   bid 0..15 : SCAN WG (l=bid>>2, q=bid&3). Owns dims q*64..q*64+63, all
//               4 gates (16 col-tiles; 8 waves x 2 tiles x 8 chunks MFMA).
//               Gate-combine via LDS gbuf (intra-WG). h exchange: 3-peer
//               rendezvous, proven R0 tagged u64 agent protocol; own 2
//               K-chunks read from LDS (swizzled), 6 peer chunks polled
//               (24 tagged u64/lane). State: thread owns (batch, dim-pair).
//   bid 16..47: helper (l=(bid-16)>>3, j=(bid-16)&7): proven streaming gx
//               GEMM, 256 active threads; idle waves barrier-match.
// All MFMA fragment/X-pair/C layouts are the R0-proven mappings verbatim.
// ---------------------------------------------------------------------------
__global__ __launch_bounds__(512)
__attribute__((amdgpu_waves_per_eu(2, 2)))
void mega_kernel(
    const float* __restrict__ hemb, const float* __restrict__ Wh,
    const float* __restrict__ lng, const float* __restrict__ lnb,
    const float* __restrict__ bgp, const unsigned short* __restrict__ Wxh,
    float* __restrict__ hout,
    u64* __restrict__ Xbuf, u64* __restrict__ Rbuf, u64* __restrict__ GXbuf,
    unsigned* __restrict__ prog, int* __restrict__ abortFlag) {
    __shared__ __align__(16) char smemBlob[83968];  // 82KB: pins 1 WG/CU
    const int bid = blockIdx.x;
    const int tid = threadIdx.x;

    if (bid < 16) {
        // ================= SCAN ROLE: layer l, dim-quarter q =================
        const int l = bid >> 2, q = bid & 3;
        const int w = tid >> 6, lane = tid & 63;
        const int quad = lane >> 4, mm = lane & 15;
        const int g = w >> 1;              // gate handled by this wave (0..3)
        const int jb0 = (w & 1) * 2;       // first of 2 owned 16-col tiles
        const int b = tid >> 5;            // owned batch (0..15)
        const int pl = tid & 31;           // owned local dim-pair (0..31)
        const int dl0 = 2 * pl;            // local dims dl0, dl0+1
        const int dg0 = q * 64 + dl0;      // global dims
        float* gb = (float*)smemBlob;                      // [4][16][64] f32
        char* hbufBase = smemBlob + 16384;                 // 2 x [16][128B] f16

        // Wh B-frags: 2 col-tiles x 8 K-chunks = 64 VGPRs (quarter of Wh / WG)
        H8 bfr[2][8];
        {
            const float* WhL = Wh + (size_t)l * DD * ND4;
#pragma unroll
            for (int tau = 0; tau < 2; ++tau) {
                const int col = g * 256 + q * 64 + (jb0 + tau) * 16 + mm;
#pragma unroll
                for (int kc = 0; kc < 8; ++kc)
#pragma unroll
                    for (int p = 0; p < 4; ++p) {
                        float f0 = WhL[(size_t)(32 * kc + 8 * quad + 2 * p) * ND4 + col];
                        float f1 = WhL[(size_t)(32 * kc + 8 * quad + 2 * p + 1) * ND4 + col];
                        bfr[tau][kc].u[p] = (unsigned)f16b(f0) | ((unsigned)f16b(f1) << 16);
                    }
            }
        }

        u64* Xl = Xbuf + (size_t)l * 4096;               // 2 parity x 2048 u64
        const u64* Rprev = Rbuf + (size_t)(l > 0 ? l - 1 : 0) * PRD * 4096;
        u64* Rcur = Rbuf + (size_t)(l < 3 ? l : 0) * PRD * 4096;
        const u64* GXl = GXbuf + (size_t)l * PGD * 16384;

        // progress-gate caches (monotone lower bounds)
        unsigned psC = 0, minPgC = 0;
        const unsigned* psP = prog + (l + 1);
        const unsigned* pgP = prog + 4 + (l + 1) * 8;

        // tagged prefetch: 8 gx (2 dims x 4 gates) + 2 residual / 2 embed
        u64 pf[8]; u64 pr[2]; float ph[2];
        auto loadSlot = [&](int t1) {
            const u64* Gp = GXl + (size_t)(t1 & (PGD - 1)) * 16384 + (size_t)b * 1024;
#pragma unroll
            for (int gg = 0; gg < 4; ++gg) {
                pf[gg * 2 + 0] = aload(Gp + gg * 256 + dg0);
                pf[gg * 2 + 1] = aload(Gp + gg * 256 + dg0 + 1);
            }
            if (l > 0) {
                const u64* Rp = Rprev + (size_t)(t1 & (PRD - 1)) * 4096 + (size_t)b * 256;
                pr[0] = aload(Rp + dg0);
                pr[1] = aload(Rp + dg0 + 1);
            } else {
                ph[0] = hemb[((size_t)b * SS + t1) * DD + dg0];
                ph[1] = hemb[((size_t)b * SS + t1) * DD + dg0 + 1];
            }
        };
        auto tagsOK = [&](unsigned tagT) {
            bool ok = true;
#pragma unroll
            for (int i = 0; i < 8; ++i) ok &= ((unsigned)(pf[i] >> 32) == tagT);
            if (l > 0) ok &= ((unsigned)(pr[0] >> 32) == tagT) &
                             ((unsigned)(pr[1] >> 32) == tagT);
            return ok;
        };

        loadSlot(0);
        float c_[2] = {0.f, 0.f}, n_[2] = {0.f, 0.f}, m_[2] = {0.f, 0.f};
        ldsBar();  // align waves before loop

        for (int t = 0; t < SS; ++t) {
            const unsigned tagT = (unsigned)(t + 1);
            // ---- 1. acquire gx (+hin), prefetched last step ----
            if (!tagsOK(tagT)) {
                int guard = 0;
                for (;;) {
                    loadSlot(t);
                    if (tagsOK(tagT)) break;
                    if (spinBail(guard, abortFlag)) break;
                }
            }
            float gxv[8], hin[2];
#pragma unroll
            for (int i = 0; i < 8; ++i) gxv[i] = __uint_as_float((unsigned)pf[i]);
#pragma unroll
            for (int r = 0; r < 2; ++r)
                hin[r] = (l > 0) ? __uint_as_float((unsigned)pr[r]) : ph[r];
            if (q == 0 && tid == 0) pstore(prog + l, (unsigned)(t + 1));

            // ---- 2. A-frags (own from LDS, 6 peer chunks polled) + MFMA ----
            f32x4 acc0 = {0.f, 0.f, 0.f, 0.f}, acc1 = {0.f, 0.f, 0.f, 0.f};
            if (t > 0) {
                const unsigned tag = (unsigned)t;
                const u64* Xp = Xl + (size_t)(t & 1) * 2048;
                H8 A[8];
                unsigned atag[8][4];
                int guard = 0;
                for (;;) {
#pragma unroll
                    for (int kc = 0; kc < 8; ++kc) {
                        if ((kc >> 1) == q) continue;   // own: from LDS below
                        const u64* cp = Xp + (size_t)(kc * 16 + quad * 4) * 16 + mm;
#pragma unroll
                        for (int j = 0; j < 4; ++j) {
                            u64 v = aload(cp + (size_t)j * 16);
                            A[kc].u[j] = (unsigned)v;
                            atag[kc][j] = (unsigned)(v >> 32);
                        }
                    }
                    bool ok = true;
#pragma unroll
                    for (int kc = 0; kc < 8; ++kc) {
                        if ((kc >> 1) == q) continue;
#pragma unroll
                        for (int j = 0; j < 4; ++j) ok &= (atag[kc][j] == tag);
                    }
                    if (ok) break;
                    if ((++guard & 255) == 0) {
                        if (guard > (1 << 18) || aflag(abortFlag)) { sflag(abortFlag); break; }
                    }
                }
                // own 2 chunks from LDS (written at t-1 phase 4, after B2)
                const char* hb = hbufBase + (size_t)(t & 1) * 2048;
#pragma unroll
                for (int kc = 0; kc < 8; ++kc)
                    if ((kc >> 1) == q)
                        A[kc].q = *(const uint4*)(hb + mm * 128 +
                                   (((kc & 1) * 64 + quad * 16) ^ ((mm & 7) << 4)));
                // prefetch t+1 AFTER the poll (poll's vmcnt must not drain it)
                loadSlot(t + 1 < SS ? t + 1 : t);
#pragma unroll
                for (int kc = 0; kc < 8; ++kc) {
                    acc0 = __builtin_amdgcn_mfma_f32_16x16x32_f16(A[kc].v, bfr[0][kc].v, acc0, 0, 0, 0);
                    acc1 = __builtin_amdgcn_mfma_f32_16x16x32_f16(A[kc].v, bfr[1][kc].v, acc1, 0, 0, 0);
                }
            } else {
                loadSlot(1);
            }

            // ---- 3. acc -> gbuf (C layout: row=batch quad*4+r, col=mm) ----
#pragma unroll
            for (int r = 0; r < 4; ++r) {
                gb[g * 1024 + (quad * 4 + r) * 64 + (jb0 + 0) * 16 + mm] = acc0[r];
                gb[g * 1024 + (quad * 4 + r) * 64 + (jb0 + 1) * 16 + mm] = acc1[r];
            }
            ldsBar();   // B1

            // ---- 4. gates for 2 owned dims; state; publish ----
            float rnew[2], hval[2];
#pragma unroll
            for (int r = 0; r < 2; ++r) {
                const int dl = dl0 + r;
                float gi = gb[0 * 1024 + b * 64 + dl] + gxv[0 * 2 + r];
                float gf = gb[1 * 1024 + b * 64 + dl] + gxv[1 * 2 + r];
                float gz = gb[2 * 1024 + b * 64 + dl] + gxv[2 * 2 + r];
                float go = gb[3 * 1024 + b * 64 + dl] + gxv[3 * 2 + r];
                float mn = fmaxf(gf + m_[r], gi);
                float ip = __expf(gi - mn);
                float fp = __expf(gf + m_[r] - mn);
                float e2z = __expf(2.f * gz);
                float th = 1.f - 2.f * __builtin_amdgcn_rcpf(e2z + 1.f);
                c_[r] = fp * c_[r] + ip * th;
                n_[r] = fp * n_[r] + ip;
                m_[r] = mn;
                float sg = __builtin_amdgcn_rcpf(1.f + __expf(-go));
                hval[r] = sg * c_[r] * __builtin_amdgcn_rcpf(fmaxf(fabsf(n_[r]), 1.f));
                rnew[r] = hin[r] + hval[r];
            }
            // h(t) -> LDS (own A-frag source for t+1), swizzled dword
            {
                char* hbN = hbufBase + (size_t)((t + 1) & 1) * 2048;
                unsigned hpack = (unsigned)f16b(hval[0]) | ((unsigned)f16b(hval[1]) << 16);
                *(unsigned*)(hbN + b * 128 + ((4 * pl) ^ ((b & 7) << 4))) = hpack;
                // publish pair to peers (tag t+1, parity (t+1)&1)
                astore(Xl + (size_t)((t + 1) & 1) * 2048 + (size_t)(q * 32 + pl) * 16 + b,
                       ((u64)tagT << 32) | (u64)hpack);
            }
            // ---- residual out ----
            if (l == 3) {
                hout[((size_t)b * SS + t) * DD + dg0] = rnew[0];
                hout[((size_t)b * SS + t) * DD + dg0 + 1] = rnew[1];
            } else {
                if (t >= PRD) {  // slot-reuse gate, cached (counters monotone)
                    unsigned needT = (unsigned)(t - PRD);
                    if (!((psC >= needT + 2) & (minPgC >= needT + 1))) {
                        int guard = 0;
                        for (;;) {
                            unsigned a = pload(psP);
                            unsigned mn8 = pload(pgP + 0);
#pragma unroll
                            for (int i = 1; i < 8; ++i) mn8 = umin2(mn8, pload(pgP + i));
                            psC = a; minPgC = mn8;
                            if ((a >= needT + 2) & (mn8 >= needT + 1)) break;
                            if (spinBail(guard, abortFlag)) break;
                        }
                    }
                }
                u64* Rq = Rcur + (size_t)(t & (PRD - 1)) * 4096 + (size_t)b * 256;
                astore(Rq + dg0, ((u64)tagT << 32) | (u64)__float_as_uint(rnew[0]));
                astore(Rq + dg0 + 1, ((u64)tagT << 32) | (u64)__float_as_uint(rnew[1]));
            }
            ldsBar();   // B2: hbuf ready for t+1; gbuf WAR protection
        }
    } else {
        // ================= HELPER ROLE: streaming gx GEMM =================
        const int hix = bid - 16;
        const int l = hix >> 3;
        const int j = hix & 7;
        if (tid >= 256) {
            // idle waves: match the active waves' barrier count exactly
            for (int t = j; t < SS; t += HLP) { __syncthreads(); __syncthreads(); }
            return;
        }
        const int w = tid >> 6, lane = tid & 63;
        const int mm = lane & 15, quad = lane >> 4;
        const int hb_ = tid >> 4, hd0 = (tid & 15) * 16;
        unsigned short (*hA)[264] = (unsigned short (*)[264])smemBlob;

        const u64* Rin = Rbuf + (size_t)(l > 0 ? l - 1 : 0) * PRD * 4096;
        u64* GXl = GXbuf + (size_t)l * PGD * 16384;
        const unsigned short* WxL = Wxh + (size_t)l * 262144;
        const float* lngL = lng + l * DD;
        const float* lnbL = lnb + l * DD;
        const float* bgL = bgp + (size_t)l * ND4;
        unsigned* myProg = prog + 4 + l * 8 + j;
        const unsigned* scanProg = prog + l;
        unsigned spC = 0;  // cached lower bound of scan progress

        for (int t = j; t < SS; t += HLP) {
            const unsigned tagT = (unsigned)(t + 1);
            // ---- 1. acquire r[l-1][t] (or embed for l==0) ----
            float rv[16];
            if (l == 0) {
                const float4* p = (const float4*)(hemb + ((size_t)hb_ * SS + t) * DD + hd0);
#pragma unroll
                for (int q4 = 0; q4 < 4; ++q4) {
                    float4 f = p[q4];
                    rv[q4 * 4 + 0] = f.x; rv[q4 * 4 + 1] = f.y;
                    rv[q4 * 4 + 2] = f.z; rv[q4 * 4 + 3] = f.w;
                }
            } else {
                const u64* Rp = Rin + (size_t)(t & (PRD - 1)) * 4096 + (size_t)tid * 16;
                int guard = 0;
                for (;;) {
                    u64 vv[16];
#pragma unroll
                    for (int i = 0; i < 16; ++i) vv[i] = aload(Rp + i);
                    bool ok = true;
#pragma unroll
                    for (int i = 0; i < 16; ++i) ok &= ((unsigned)(vv[i] >> 32) == tagT);
                    if (ok) {
#pragma unroll
                        for (int i = 0; i < 16; ++i) rv[i] = __uint_as_float((unsigned)vv[i]);
                        break;
                    }
                    if (spinBail(guard, abortFlag)) {
#pragma unroll
                        for (int i = 0; i < 16; ++i) rv[i] = 0.f;
                        break;
                    }
                }
            }
            // ---- 2. LN stats (16 threads per batch, shfl-xor reduce) ----
            float s = 0.f, ssq = 0.f;
#pragma unroll
            for (int i = 0; i < 16; ++i) { s += rv[i]; ssq += rv[i] * rv[i]; }
#pragma unroll
            for (int msk = 1; msk < 16; msk <<= 1) {
                s += __shfl_xor(s, msk);
                ssq += __shfl_xor(ssq, msk);
            }
            float muv = s * (1.f / 256.f);
            float rsv = rsqrtf(fmaxf(ssq * (1.f / 256.f) - muv * muv, 0.f) + 1e-5f);
            // ---- 3. LN -> fp16 -> LDS (A-matrix rows = batches) ----
            {
                __align__(16) unsigned short ov[16];
#pragma unroll
                for (int i = 0; i < 16; ++i)
                    ov[i] = f16b((rv[i] - muv) * rsv * lngL[hd0 + i] + lnbL[hd0 + i]);
                *(uint4*)&hA[hb_][hd0] = *(uint4*)&ov[0];
                *(uint4*)&hA[hb_][hd0 + 8] = *(uint4*)&ov[8];
            }
            __syncthreads();
            // early post: this sync covers every thread's R-read for token t
            if (tid == 0) pstore(myProg, (unsigned)(t + 1));
            // ---- 4. A-frags from LDS ----
            H8 A[8];
#pragma unroll
            for (int kc = 0; kc < 8; ++kc)
                A[kc].q = *(const uint4*)&hA[mm][kc * 32 + quad * 8];
            // ---- 5. 16 tiles x 8 chunks MFMA, B streamed from L2 ----
            f32x4 acc[16];
            const unsigned short* WxW = WxL + (size_t)w * 16 * 4096;
#pragma unroll
            for (int n = 0; n < 16; ++n) {
                const unsigned short* bp = WxW + (size_t)n * 4096 + (size_t)lane * 8;
                f32x4 a = {0.f, 0.f, 0.f, 0.f};
#pragma unroll
                for (int kc = 0; kc < 8; ++kc) {
                    H8 B;
                    B.q = *(const uint4*)(bp + (size_t)kc * 512);
                    a = __builtin_amdgcn_mfma_f32_16x16x32_f16(A[kc].v, B.v, a, 0, 0, 0);
                }
                acc[n] = a;
            }
            // ---- 6. slot-reuse gate (cached), then write GX ----
            if (t >= PGD) {
                unsigned need = (unsigned)(t - PGD) + 2;
                if (spC < need) {
                    int guard = 0;
                    for (;;) {
                        unsigned v = pload(scanProg);
                        spC = v;
                        if (v >= need) break;
                        if (spinBail(guard, abortFlag)) break;
                    }
                }
            }
            u64* Gq = GXl + (size_t)(t & (PGD - 1)) * 16384;
#pragma unroll
            for (int n = 0; n < 16; ++n) {
                int c = (w * 16 + n) * 16 + mm;
                float bgv = bgL[c];
                f32x4 a = acc[n];
#pragma unroll
                for (int r = 0; r < 4; ++r)
                    astore(Gq + (size_t)(quad * 4 + r) * 1024 + c,
                           ((u64)tagT << 32) | (u64)__float_as_uint(a[r] + bgv));
            }
            __syncthreads();  // covers hA WAR for next token
        }
    }
}

// ---------------------------------------------------------------------------
// final: out[b] = r3[b][S-1][:] . fc_W + fc_b
// ---------------------------------------------------------------------------
__global__ void final_kernel(const float* __restrict__ h, const float* __restrict__ fcW,
                             const float* __restrict__ fcb, float* __restrict__ out) {
    int b = blockIdx.x, lane = threadIdx.x;
    const float4 hv = *(const float4*)(h + ((size_t)b * SS + (SS - 1)) * DD + lane * 4);
    const float4 wv = *(const float4*)(fcW + lane * 4);
    float s = hv.x * wv.x + hv.y * wv.y + hv.z * wv.z + hv.w * wv.w;
#pragma unroll
    for (int off = 32; off; off >>= 1) s += __shfl_down(s, off);
    if (lane == 0) out[b] = s + fcb[0];
}

// ---------------------------------------------------------------------------
extern "C" void kernel_launch(void* const* d_in, const int* in_sizes, int n_in,
                              void* d_out, int out_size, void* d_ws, size_t ws_size,
                              hipStream_t stream) {
    const float* x   = (const float*)d_in[0];
    const float* tf  = (const float*)d_in[1];
    const float* inW = (const float*)d_in[2];
    const float* inb = (const float*)d_in[3];
    const float* lng = (const float*)d_in[4];
    const float* lnb = (const float*)d_in[5];
    const float* Wx  = (const float*)d_in[6];
    const float* Wh  = (const float*)d_in[7];
    const float* bg  = (const float*)d_in[8];
    const float* fcW = (const float*)d_in[9];
    const float* fcb = (const float*)d_in[10];
    float* out = (float*)d_out;

    const size_t nTok = (size_t)BB * SS;
    float* hemb = (float*)d_ws;                                   // 8,388,608 f
    float* hout = hemb + nTok * DD;                               // 8,388,608 f
    unsigned short* Wxh = (unsigned short*)(hout + nTok * DD);    // 1,048,576 us
    u64* Xbuf = (u64*)(Wxh + 1048576);                            // 4 * 2 * 2048
    u64* Rbuf = Xbuf + 4 * 4096;                                  // 3*16*4096
    u64* GXbuf = Rbuf + 3 * PRD * 4096;                           // 4*8*16384
    // prog area: [0..3]=scan progress, [4..35]=helper progress, [40]=abort
    unsigned* prog = (unsigned*)(GXbuf + 4 * PGD * 16384);
    int* abortFlag = (int*)(prog + 40);

    const size_t needed = (size_t)((char*)(prog + 64) - (char*)d_ws);
    if (ws_size < needed) return;  // fail visibly instead of corrupting

    hipMemsetAsync(prog, 0, 64 * sizeof(unsigned), stream);
    // X/R/GX need no init: 0xAA poison never matches a tag in [1,2048]

    embed_kernel<<<nTok, DD, 0, stream>>>(x, tf, inW, inb, hemb);
    wxprep_kernel<<<4 * 64, 64, 0, stream>>>(Wx, Wxh);
    mega_kernel<<<48, 512, 0, stream>>>(hemb, Wh, lng, lnb, bg, Wxh, hout,
                                        Xbuf, Rbuf, GXbuf, prog, abortFlag);
    final_kernel<<<BB, 64, 0, stream>>>(hout, fcW, fcb, out);
    (void)in_sizes; (void)n_in; (void)out_size;
}

// Round 11
// 10001.060 us; speedup vs baseline: 4.6410x; 1.9369x over previous
//
#include <hip/hip_runtime.h>

// Problem constants
#define BB 16
#define SS 2048
#define DD 256
#define ND4 1024   // 4*D
#define PRD 16     // R-buffer slot depth (residual stream)
#define PGD 8      // GX-buffer slot depth (gate pre-activations)
#define HLP 8      // helper WGs per layer (one per GX slot)

typedef __attribute__((ext_vector_type(8))) _Float16 half8;
typedef __attribute__((ext_vector_type(4))) float f32x4;
typedef unsigned long long u64;
union H8 { half8 v; unsigned int u[4]; uint4 q; };

__device__ __forceinline__ u64 aload(const u64* p) {
    return __hip_atomic_load(p, __ATOMIC_RELAXED, __HIP_MEMORY_SCOPE_AGENT);
}
__device__ __forceinline__ void astore(u64* p, u64 v) {
    __hip_atomic_store(p, v, __ATOMIC_RELAXED, __HIP_MEMORY_SCOPE_AGENT);
}
__device__ __forceinline__ unsigned pload(const unsigned* p) {
    return __hip_atomic_load(p, __ATOMIC_RELAXED, __HIP_MEMORY_SCOPE_AGENT);
}
__device__ __forceinline__ void pstore(unsigned* p, unsigned v) {
    __hip_atomic_store(p, v, __ATOMIC_RELAXED, __HIP_MEMORY_SCOPE_AGENT);
}
__device__ __forceinline__ int aflag(int* p) {
    return __hip_atomic_load(p, __ATOMIC_RELAXED, __HIP_MEMORY_SCOPE_AGENT);
}
__device__ __forceinline__ void sflag(int* p) {
    __hip_atomic_store(p, 1, __ATOMIC_RELAXED, __HIP_MEMORY_SCOPE_AGENT);
}
__device__ __forceinline__ unsigned short f16b(float x) {
    union { _Float16 h; unsigned short u; } c; c.h = (_Float16)x; return c.u;
}
__device__ __forceinline__ unsigned umin2(unsigned a, unsigned b) { return a < b ? a : b; }
// LDS-only barrier: __syncthreads() emits a full vmcnt(0) drain [HIP-compiler];
// scan's barriers only protect LDS, so lgkmcnt(0) + raw s_barrier suffices and
// leaves the agent prefetch/stores in flight.
__device__ __forceinline__ void ldsBar() {
    asm volatile("s_waitcnt lgkmcnt(0)" ::: "memory");
    __builtin_amdgcn_s_barrier();
}
// spin guard with backoff (steady-state: first-try hit)
__device__ __forceinline__ bool spinBail(int& guard, int* af) {
    if ((++guard & 63) == 0) {
        __builtin_amdgcn_s_sleep(1);
        if (guard > (1 << 18) || aflag(af)) { sflag(af); return true; }
    }
    return false;
}

// ---------------------------------------------------------------------------
// embed: h0 = [x | tf] @ in_W + in_b
// ---------------------------------------------------------------------------
__global__ void embed_kernel(const float* __restrict__ x, const float* __restrict__ tf,
                             const float* __restrict__ inW, const float* __restrict__ inb,
                             float* __restrict__ h) {
    int tok = blockIdx.x, d = threadIdx.x;
    float xv = x[tok];
    float acc = inb[d] + xv * inW[d];
#pragma unroll
    for (int c = 0; c < 6; ++c)
        acc = fmaf(tf[tok * 6 + c], inW[(c + 1) * DD + d], acc);
    h[(size_t)tok * DD + d] = acc;
}

// ---------------------------------------------------------------------------
// Wx -> fp16 B-fragment order: Wxh[((l*64+G)*8+kc)*64 + lane][8]
// ---------------------------------------------------------------------------
__global__ void wxprep_kernel(const float* __restrict__ Wx, unsigned short* __restrict__ Wxh) {
    int l = blockIdx.x >> 6, G = blockIdx.x & 63;
    int lane = threadIdx.x, quad = lane >> 4, mm = lane & 15;
    const float* W = Wx + (size_t)l * DD * ND4;
    unsigned short* o = Wxh + (size_t)blockIdx.x * 4096;
#pragma unroll
    for (int kc = 0; kc < 8; ++kc) {
        __align__(16) unsigned short tmp[8];
#pragma unroll
        for (int i = 0; i < 8; ++i)
            tmp[i] = f16b(W[(size_t)(kc * 32 + quad * 8 + i) * ND4 + G * 16 + mm]);
        *(uint4*)(o + ((size_t)kc * 64 + lane) * 8) = *(uint4*)tmp;
    }
}

// ---------------------------------------------------------------------------
// Mega kernel R11 = R10 with the VGPR cap actually lifted.
// R10 failure: VGPR_Count=128 (attribute ignored) -> Wh spilled to scratch.
// Fix: __launch_bounds__(512, 2) (2 waves/EU min -> 256-VGPR budget, the
// documented mechanism) + drop the atag[8][4] array (saves 32 VGPRs; tag
// check folded into the load loop). Peak demand ~165 < 256. Everything else
// byte-identical to R10 (which PASSED -> layouts proven).
//   bid 0..15 : SCAN WG (l=bid>>2, q=bid&3): dims q*64..+63, all 4 gates;
//               3-peer tagged-u64 h rendezvous; own chunks via LDS.
//   bid 16..47: helper (l, j): proven streaming gx GEMM.
// ---------------------------------------------------------------------------
__global__ __launch_bounds__(512, 2)
void mega_kernel(
    const float* __restrict__ hemb, const float* __restrict__ Wh,
    const float* __restrict__ lng, const float* __restrict__ lnb,
    const float* __restrict__ bgp, const unsigned short* __restrict__ Wxh,
    float* __restrict__ hout,
    u64* __restrict__ Xbuf, u64* __restrict__ Rbuf, u64* __restrict__ GXbuf,
    unsigned* __restrict__ prog, int* __restrict__ abortFlag) {
    __shared__ __align__(16) char smemBlob[83968];  // 82KB: pins 1 WG/CU
    const int bid = blockIdx.x;
    const int tid = threadIdx.x;

    if (bid < 16) {
        // ================= SCAN ROLE: layer l, dim-quarter q =================
        const int l = bid >> 2, q = bid & 3;
        const int w = tid >> 6, lane = tid & 63;
        const int quad = lane >> 4, mm = lane & 15;
        const int g = w >> 1;              // gate handled by this wave (0..3)
        const int jb0 = (w & 1) * 2;       // first of 2 owned 16-col tiles
        const int b = tid >> 5;            // owned batch (0..15)
        const int pl = tid & 31;           // owned local dim-pair (0..31)
        const int dl0 = 2 * pl;            // local dims dl0, dl0+1
        const int dg0 = q * 64 + dl0;      // global dims
        float* gb = (float*)smemBlob;                      // [4][16][64] f32
        char* hbufBase = smemBlob + 16384;                 // 2 x [16][128B] f16

        // Wh B-frags: 2 col-tiles x 8 K-chunks = 64 VGPRs (quarter of Wh / WG)
        H8 bfr[2][8];
        {
            const float* WhL = Wh + (size_t)l * DD * ND4;
#pragma unroll
            for (int tau = 0; tau < 2; ++tau) {
                const int col = g * 256 + q * 64 + (jb0 + tau) * 16 + mm;
#pragma unroll
                for (int kc = 0; kc < 8; ++kc)
#pragma unroll
                    for (int p = 0; p < 4; ++p) {
                        float f0 = WhL[(size_t)(32 * kc + 8 * quad + 2 * p) * ND4 + col];
                        float f1 = WhL[(size_t)(32 * kc + 8 * quad + 2 * p + 1) * ND4 + col];
                        bfr[tau][kc].u[p] = (unsigned)f16b(f0) | ((unsigned)f16b(f1) << 16);
                    }
            }
        }

        u64* Xl = Xbuf + (size_t)l * 4096;               // 2 parity x 2048 u64
        const u64* Rprev = Rbuf + (size_t)(l > 0 ? l - 1 : 0) * PRD * 4096;
        u64* Rcur = Rbuf + (size_t)(l < 3 ? l : 0) * PRD * 4096;
        const u64* GXl = GXbuf + (size_t)l * PGD * 16384;

        // progress-gate caches (monotone lower bounds)
        unsigned psC = 0, minPgC = 0;
        const unsigned* psP = prog + (l + 1);
        const unsigned* pgP = prog + 4 + (l + 1) * 8;

        // tagged prefetch: 8 gx (2 dims x 4 gates) + 2 residual / 2 embed
        u64 pf[8]; u64 pr[2]; float ph[2];
        auto loadSlot = [&](int t1) {
            const u64* Gp = GXl + (size_t)(t1 & (PGD - 1)) * 16384 + (size_t)b * 1024;
#pragma unroll
            for (int gg = 0; gg < 4; ++gg) {
                pf[gg * 2 + 0] = aload(Gp + gg * 256 + dg0);
                pf[gg * 2 + 1] = aload(Gp + gg * 256 + dg0 + 1);
            }
            if (l > 0) {
                const u64* Rp = Rprev + (size_t)(t1 & (PRD - 1)) * 4096 + (size_t)b * 256;
                pr[0] = aload(Rp + dg0);
                pr[1] = aload(Rp + dg0 + 1);
            } else {
                ph[0] = hemb[((size_t)b * SS + t1) * DD + dg0];
                ph[1] = hemb[((size_t)b * SS + t1) * DD + dg0 + 1];
            }
        };
        auto tagsOK = [&](unsigned tagT) {
            bool ok = true;
#pragma unroll
            for (int i = 0; i < 8; ++i) ok &= ((unsigned)(pf[i] >> 32) == tagT);
            if (l > 0) ok &= ((unsigned)(pr[0] >> 32) == tagT) &
                             ((unsigned)(pr[1] >> 32) == tagT);
            return ok;
        };

        loadSlot(0);
        float c_[2] = {0.f, 0.f}, n_[2] = {0.f, 0.f}, m_[2] = {0.f, 0.f};
        ldsBar();  // align waves before loop

        for (int t = 0; t < SS; ++t) {
            const unsigned tagT = (unsigned)(t + 1);
            // ---- 1. acquire gx (+hin), prefetched last step ----
            if (!tagsOK(tagT)) {
                int guard = 0;
                for (;;) {
                    loadSlot(t);
                    if (tagsOK(tagT)) break;
                    if (spinBail(guard, abortFlag)) break;
                }
            }
            float gxv[8], hin[2];
#pragma unroll
            for (int i = 0; i < 8; ++i) gxv[i] = __uint_as_float((unsigned)pf[i]);
#pragma unroll
            for (int r = 0; r < 2; ++r)
                hin[r] = (l > 0) ? __uint_as_float((unsigned)pr[r]) : ph[r];
            if (q == 0 && tid == 0) pstore(prog + l, (unsigned)(t + 1));

            // ---- 2. A-frags (own from LDS, 6 peer chunks polled) + MFMA ----
            f32x4 acc0 = {0.f, 0.f, 0.f, 0.f}, acc1 = {0.f, 0.f, 0.f, 0.f};
            if (t > 0) {
                const unsigned tag = (unsigned)t;
                const u64* Xp = Xl + (size_t)(t & 1) * 2048;
                H8 A[8];
                int guard = 0;
                for (;;) {
                    bool ok = true;
#pragma unroll
                    for (int kc = 0; kc < 8; ++kc) {
                        if ((kc >> 1) == q) continue;   // own: from LDS below
                        const u64* cp = Xp + (size_t)(kc * 16 + quad * 4) * 16 + mm;
#pragma unroll
                        for (int j = 0; j < 4; ++j) {
                            u64 v = aload(cp + (size_t)j * 16);
                            A[kc].u[j] = (unsigned)v;
                            ok &= ((unsigned)(v >> 32) == tag);
                        }
                    }
                    if (ok) break;
                    if ((++guard & 255) == 0) {
                        if (guard > (1 << 18) || aflag(abortFlag)) { sflag(abortFlag); break; }
                    }
                }
                // own 2 chunks from LDS (written at t-1 phase 4, after B2)
                const char* hb = hbufBase + (size_t)(t & 1) * 2048;
#pragma unroll
                for (int kc = 0; kc < 8; ++kc)
                    if ((kc >> 1) == q)
                        A[kc].q = *(const uint4*)(hb + mm * 128 +
                                   (((kc & 1) * 64 + quad * 16) ^ ((mm & 7) << 4)));
                // prefetch t+1 AFTER the poll (poll's vmcnt must not drain it)
                loadSlot(t + 1 < SS ? t + 1 : t);
#pragma unroll
                for (int kc = 0; kc < 8; ++kc) {
                    acc0 = __builtin_amdgcn_mfma_f32_16x16x32_f16(A[kc].v, bfr[0][kc].v, acc0, 0, 0, 0);
                    acc1 = __builtin_amdgcn_mfma_f32_16x16x32_f16(A[kc].v, bfr[1][kc].v, acc1, 0, 0, 0);
                }
            } else {
                loadSlot(1);
            }

            // ---- 3. acc -> gbuf (C layout: row=batch quad*4+r, col=mm) ----
#pragma unroll
            for (int r = 0; r < 4; ++r) {
                gb[g * 1024 + (quad * 4 + r) * 64 + (jb0 + 0) * 16 + mm] = acc0[r];
                gb[g * 1024 + (quad * 4 + r) * 64 + (jb0 + 1) * 16 + mm] = acc1[r];
            }
            ldsBar();   // B1

            // ---- 4. gates for 2 owned dims; state; publish ----
            float rnew[2], hval[2];
#pragma unroll
            for (int r = 0; r < 2; ++r) {
                const int dl = dl0 + r;
                float gi = gb[0 * 1024 + b * 64 + dl] + gxv[0 * 2 + r];
                float gf = gb[1 * 1024 + b * 64 + dl] + gxv[1 * 2 + r];
                float gz = gb[2 * 1024 + b * 64 + dl] + gxv[2 * 2 + r];
                float go = gb[3 * 1024 + b * 64 + dl] + gxv[3 * 2 + r];
                float mn = fmaxf(gf + m_[r], gi);
                float ip = __expf(gi - mn);
                float fp = __expf(gf + m_[r] - mn);
                float e2z = __expf(2.f * gz);
                float th = 1.f - 2.f * __builtin_amdgcn_rcpf(e2z + 1.f);
                c_[r] = fp * c_[r] + ip * th;
                n_[r] = fp * n_[r] + ip;
                m_[r] = mn;
                float sg = __builtin_amdgcn_rcpf(1.f + __expf(-go));
                hval[r] = sg * c_[r] * __builtin_amdgcn_rcpf(fmaxf(fabsf(n_[r]), 1.f));
                rnew[r] = hin[r] + hval[r];
            }
            // h(t) -> LDS (own A-frag source for t+1), swizzled dword
            {
                char* hbN = hbufBase + (size_t)((t + 1) & 1) * 2048;
                unsigned hpack = (unsigned)f16b(hval[0]) | ((unsigned)f16b(hval[1]) << 16);
                *(unsigned*)(hbN + b * 128 + ((4 * pl) ^ ((b & 7) << 4))) = hpack;
                // publish pair to peers (tag t+1, parity (t+1)&1)
                astore(Xl + (size_t)((t + 1) & 1) * 2048 + (size_t)(q * 32 + pl) * 16 + b,
                       ((u64)tagT << 32) | (u64)hpack);
            }
            // ---- residual out ----
            if (l == 3) {
                hout[((size_t)b * SS + t) * DD + dg0] = rnew[0];
                hout[((size_t)b * SS + t) * DD + dg0 + 1] = rnew[1];
            } else {
                if (t >= PRD) {  // slot-reuse gate, cached (counters monotone)
                    unsigned needT = (unsigned)(t - PRD);
                    if (!((psC >= needT + 2) & (minPgC >= needT + 1))) {
                        int guard = 0;
                        for (;;) {
                            unsigned a = pload(psP);
                            unsigned mn8 = pload(pgP + 0);
#pragma unroll
                            for (int i = 1; i < 8; ++i) mn8 = umin2(mn8, pload(pgP + i));
                            psC = a; minPgC = mn8;
                            if ((a >= needT + 2) & (mn8 >= needT + 1)) break;
                            if (spinBail(guard, abortFlag)) break;
                        }
                    }
                }
                u64* Rq = Rcur + (size_t)(t & (PRD - 1)) * 4096 + (size_t)b * 256;
                astore(Rq + dg0, ((u64)tagT << 32) | (u64)__float_as_uint(rnew[0]));
                astore(Rq + dg0 + 1, ((u64)tagT << 32) | (u64)__float_as_uint(rnew[1]));
            }
            ldsBar();   // B2: hbuf ready for t+1; gbuf WAR protection
        }
    } else {
        // ================= HELPER ROLE: streaming gx GEMM =================
        const int hix = bid - 16;
        const int l = hix >> 3;
        const int j = hix & 7;
        if (tid >= 256) {
            // idle waves: match the active waves' barrier count exactly
            for (int t = j; t < SS; t += HLP) { __syncthreads(); __syncthreads(); }
            return;
        }
        const int w = tid >> 6, lane = tid & 63;
        const int mm = lane & 15, quad = lane >> 4;
        const int hb_ = tid >> 4, hd0 = (tid & 15) * 16;
        unsigned short (*hA)[264] = (unsigned short (*)[264])smemBlob;

        const u64* Rin = Rbuf + (size_t)(l > 0 ? l - 1 : 0) * PRD * 4096;
        u64* GXl = GXbuf + (size_t)l * PGD * 16384;
        const unsigned short* WxL = Wxh + (size_t)l * 262144;
        const float* lngL = lng + l * DD;
        const float* lnbL = lnb + l * DD;
        const float* bgL = bgp + (size_t)l * ND4;
        unsigned* myProg = prog + 4 + l * 8 + j;
        const unsigned* scanProg = prog + l;
        unsigned spC = 0;  // cached lower bound of scan progress

        for (int t = j; t < SS; t += HLP) {
            const unsigned tagT = (unsigned)(t + 1);
            // ---- 1. acquire r[l-1][t] (or embed for l==0) ----
            float rv[16];
            if (l == 0) {
                const float4* p = (const float4*)(hemb + ((size_t)hb_ * SS + t) * DD + hd0);
#pragma unroll
                for (int q4 = 0; q4 < 4; ++q4) {
                    float4 f = p[q4];
                    rv[q4 * 4 + 0] = f.x; rv[q4 * 4 + 1] = f.y;
                    rv[q4 * 4 + 2] = f.z; rv[q4 * 4 + 3] = f.w;
                }
            } else {
                const u64* Rp = Rin + (size_t)(t & (PRD - 1)) * 4096 + (size_t)tid * 16;
                int guard = 0;
                for (;;) {
                    u64 vv[16];
#pragma unroll
                    for (int i = 0; i < 16; ++i) vv[i] = aload(Rp + i);
                    bool ok = true;
#pragma unroll
                    for (int i = 0; i < 16; ++i) ok &= ((unsigned)(vv[i] >> 32) == tagT);
                    if (ok) {
#pragma unroll
                        for (int i = 0; i < 16; ++i) rv[i] = __uint_as_float((unsigned)vv[i]);
                        break;
                    }
                    if (spinBail(guard, abortFlag)) {
#pragma unroll
                        for (int i = 0; i < 16; ++i) rv[i] = 0.f;
                        break;
                    }
                }
            }
            // ---- 2. LN stats (16 threads per batch, shfl-xor reduce) ----
            float s = 0.f, ssq = 0.f;
#pragma unroll
            for (int i = 0; i < 16; ++i) { s += rv[i]; ssq += rv[i] * rv[i]; }
#pragma unroll
            for (int msk = 1; msk < 16; msk <<= 1) {
                s += __shfl_xor(s, msk);
                ssq += __shfl_xor(ssq, msk);
            }
            float muv = s * (1.f / 256.f);
            float rsv = rsqrtf(fmaxf(ssq * (1.f / 256.f) - muv * muv, 0.f) + 1e-5f);
            // ---- 3. LN -> fp16 -> LDS (A-matrix rows = batches) ----
            {
                __align__(16) unsigned short ov[16];
#pragma unroll
                for (int i = 0; i < 16; ++i)
                    ov[i] = f16b((rv[i] - muv) * rsv * lngL[hd0 + i] + lnbL[hd0 + i]);
                *(uint4*)&hA[hb_][hd0] = *(uint4*)&ov[0];
                *(uint4*)&hA[hb_][hd0 + 8] = *(uint4*)&ov[8];
            }
            __syncthreads();
            // early post: this sync covers every thread's R-read for token t
            if (tid == 0) pstore(myProg, (unsigned)(t + 1));
            // ---- 4. A-frags from LDS ----
            H8 A[8];
#pragma unroll
            for (int kc = 0; kc < 8; ++kc)
                A[kc].q = *(const uint4*)&hA[mm][kc * 32 + quad * 8];
            // ---- 5. 16 tiles x 8 chunks MFMA, B streamed from L2 ----
            f32x4 acc[16];
            const unsigned short* WxW = WxL + (size_t)w * 16 * 4096;
#pragma unroll
            for (int n = 0; n < 16; ++n) {
                const unsigned short* bp = WxW + (size_t)n * 4096 + (size_t)lane * 8;
                f32x4 a = {0.f, 0.f, 0.f, 0.f};
#pragma unroll
                for (int kc = 0; kc < 8; ++kc) {
                    H8 B;
                    B.q = *(const uint4*)(bp + (size_t)kc * 512);
                    a = __builtin_amdgcn_mfma_f32_16x16x32_f16(A[kc].v, B.v, a, 0, 0, 0);
                }
                acc[n] = a;
            }
            // ---- 6. slot-reuse gate (cached), then write GX ----
            if (t >= PGD) {
                unsigned need = (unsigned)(t - PGD) + 2;
                if (spC < need) {
                    int guard = 0;
                    for (;;) {
                        unsigned v = pload(scanProg);
                        spC = v;
                        if (v >= need) break;
                        if (spinBail(guard, abortFlag)) break;
                    }
                }
            }
            u64* Gq = GXl + (size_t)(t & (PGD - 1)) * 16384;
#pragma unroll
            for (int n = 0; n < 16; ++n) {
                int c = (w * 16 + n) * 16 + mm;
                float bgv = bgL[c];
                f32x4 a = acc[n];
#pragma unroll
                for (int r = 0; r < 4; ++r)
                    astore(Gq + (size_t)(quad * 4 + r) * 1024 + c,
                           ((u64)tagT << 32) | (u64)__float_as_uint(a[r] + bgv));
            }
            __syncthreads();  // covers hA WAR for next token
        }
    }
}

// ---------------------------------------------------------------------------
// final: out[b] = r3[b][S-1][:] . fc_W + fc_b
// ---------------------------------------------------------------------------
__global__ void final_kernel(const float* __restrict__ h, const float* __restrict__ fcW,
                             const float* __restrict__ fcb, float* __restrict__ out) {
    int b = blockIdx.x, lane = threadIdx.x;
    const float4 hv = *(const float4*)(h + ((size_t)b * SS + (SS - 1)) * DD + lane * 4);
    const float4 wv = *(const float4*)(fcW + lane * 4);
    float s = hv.x * wv.x + hv.y * wv.y + hv.z * wv.z + hv.w * wv.w;
#pragma unroll
    for (int off = 32; off; off >>= 1) s += __shfl_down(s, off);
    if (lane == 0) out[b] = s + fcb[0];
}

// ---------------------------------------------------------------------------
extern "C" void kernel_launch(void* const* d_in, const int* in_sizes, int n_in,
                              void* d_out, int out_size, void* d_ws, size_t ws_size,
                              hipStream_t stream) {
    const float* x   = (const float*)d_in[0];
    const float* tf  = (const float*)d_in[1];
    const float* inW = (const float*)d_in[2];
    const float* inb = (const float*)d_in[3];
    const float* lng = (const float*)d_in[4];
    const float* lnb = (const float*)d_in[5];
    const float* Wx  = (const float*)d_in[6];
    const float* Wh  = (const float*)d_in[7];
    const float* bg  = (const float*)d_in[8];
    const float* fcW = (const float*)d_in[9];
    const float* fcb = (const float*)d_in[10];
    float* out = (float*)d_out;

    const size_t nTok = (size_t)BB * SS;
    float* hemb = (float*)d_ws;                                   // 8,388,608 f
    float* hout = hemb + nTok * DD;                               // 8,388,608 f
    unsigned short* Wxh = (unsigned short*)(hout + nTok * DD);    // 1,048,576 us
    u64* Xbuf = (u64*)(Wxh + 1048576);                            // 4 * 2 * 2048
    u64* Rbuf = Xbuf + 4 * 4096;                                  // 3*16*4096
    u64* GXbuf = Rbuf + 3 * PRD * 4096;                           // 4*8*16384
    // prog area: [0..3]=scan progress, [4..35]=helper progress, [40]=abort
    unsigned* prog = (unsigned*)(GXbuf + 4 * PGD * 16384);
    int* abortFlag = (int*)(prog + 40);

    const size_t needed = (size_t)((char*)(prog + 64) - (char*)d_ws);
    if (ws_size < needed) return;  // fail visibly instead of corrupting

    hipMemsetAsync(prog, 0, 64 * sizeof(unsigned), stream);
    // X/R/GX need no init: 0xAA poison never matches a tag in [1,2048]

    embed_kernel<<<nTok, DD, 0, stream>>>(x, tf, inW, inb, hemb);
    wxprep_kernel<<<4 * 64, 64, 0, stream>>>(Wx, Wxh);
    mega_kernel<<<48, 512, 0, stream>>>(hemb, Wh, lng, lnb, bg, Wxh, hout,
                                        Xbuf, Rbuf, GXbuf, prog, abortFlag);
    final_kernel<<<BB, 64, 0, stream>>>(hout, fcW, fcb, out);
    (void)in_sizes; (void)n_in; (void)out_size;
}